// Round 1
// 2128.607 us; speedup vs baseline: 1.0308x; 1.0308x over previous
//
#include <hip/hip_runtime.h>
#include <stdint.h>

#define BN_ 2
#define NPT 16384
#define MPT 8192
#define NROI 128
#define KP 2048

typedef unsigned long long u64;
typedef unsigned u32;

// ---- workspace layout (float offsets) ----
#define FEATS_LEN (4096*352)
#define CNTR_OFF  (FEATS_LEN)
#define CNTC_OFF  (CNTR_OFF + 4096)
#define FRAW_OFF  (CNTC_OFF + 4096)
#define FRAW_LEN  (BN_*NPT*32)
#define GC3_OFF   (FRAW_OFF + FRAW_LEN)
#define GC3_LEN   (BN_*MPT*64)
#define FLAGS_F_OFF (GC3_OFF + GC3_LEN)      // flags (bytes) at this float offset
#define CW_OFF    (FLAGS_F_OFF + (BN_*NPT)/4) // float4 compacted coords
#define OUT_KP_OFF (4096*128)                // keypoints region inside d_out

// ---------------- helpers ----------------
__device__ __forceinline__ u32 ordf(float f) {
    u32 b = __float_as_uint(f);
    return b ^ ((u32)(((int)b) >> 31) | 0x80000000u);
}
template <int CTRL>
__device__ __forceinline__ u32 dppmov(u32 v) {
    return (u32)__builtin_amdgcn_update_dpp((int)v, (int)v, CTRL, 0xF, 0xF, false);
}
// Wave64 max via DPP; result broadcast via readlane(63).
__device__ __forceinline__ u32 wave_umax_dpp(u32 v) {
#define STG(C) { u32 o = dppmov<C>(v); v = (o > v) ? o : v; }
    STG(0x111) STG(0x112) STG(0x114) STG(0x118) STG(0x142) STG(0x143)
#undef STG
    return (u32)__builtin_amdgcn_readlane((int)v, 63);
}

// Pack a wave candidate into one u64 so the 8-way block combine is 7 u64 maxes.
// gid < 16384 (14 bits); ord dominates, then inv14 (= min gid), wave bits never
// decide (gids unique across waves).
__device__ __forceinline__ u64 pack_key(u32 maxOrd, u32 maxInv, int w) {
    u32 inv14 = maxInv - 0xFFFFC000u;   // maxInv = 0xFFFFFFFF - gid  ->  0x3FFF - gid
    return ((u64)maxOrd << 17) | ((u64)inv14 << 3) | (u64)(u32)w;
}

// ---------------- K1: ROI validity flags (bit-exact vs reference) ----------------
__global__ void k_flags(const float* __restrict__ pts, const float* __restrict__ bbox,
                        unsigned char* __restrict__ flags) {
#pragma clang fp contract(off)
    __shared__ float rx[NROI], ry[NROI], rz[NROI], rt[NROI];
    int b = blockIdx.x >> 6;
    int t = threadIdx.x;
    if (t < NROI) {
        const float* rr = bbox + (size_t)(b * NROI + t) * 7;
        rx[t] = rr[0]; ry[t] = rr[1]; rz[t] = rr[2];
        float hx = rr[3] * 0.5f, hy = rr[4] * 0.5f, hz = rr[5] * 0.5f;
        rt[t] = sqrtf(((hx * hx) + (hy * hy)) + (hz * hz)) + 2.4f;
    }
    __syncthreads();
    int p = (blockIdx.x & 63) * 256 + t;
    const float* pr = pts + (size_t)(b * NPT + p) * 5;
    float x = pr[0], y = pr[1], z = pr[2];
    float mind = 3.4e38f, th = 0.f;
    for (int r = 0; r < NROI; ++r) {
        float dx = x - rx[r], dy = y - ry[r], dz = z - rz[r];
        float ds = sqrtf(((dx * dx) + (dy * dy)) + (dz * dz));
        if (ds < mind) { mind = ds; th = rt[r]; }   // strict < : first-min == np.argmin
    }
    flags[b * NPT + p] = (mind < th) ? 1 : 0;
}

// ---------------- FPS inner loop, compile-time slot count NS ----------------------
// R4: 512 threads = 8 waves = 2 waves/SIMD. Per-SIMD inner-loop issue unchanged
// (2 waves x NS/2) but the two waves interleave, hiding the DPP chains / LDS /
// winner-load latency that was fully exposed at 1 wave/SIMD. Block combine over
// 8 wave candidates done as 7 branchless u64 maxes on packed keys.
template <int NS>
__device__ __forceinline__ void fps_loop(
    int t, int lane, int w, int V,
    const float4* __restrict__ cw,
    u64 (*rk64)[8],                   // LDS, [2][8] packed candidate keys
    float* kbuf,                      // LDS, KP*3
    float* __restrict__ kout) {
#pragma clang fp contract(off)
    float px[NS], py[NS], pz[NS], d[NS];
#pragma unroll
    for (int j = 0; j < NS; ++j) {
        int id = (j << 9) + t;
        bool in = id < V;
        float4 q = in ? cw[id] : make_float4(1e18f, 1e18f, 1e18f, 0.f);
        px[j] = q.x; py[j] = q.y; pz[j] = q.z;
        d[j]  = in ? 1e10f : -3.0e38f;
    }

    // prime: argmax over initial d (ties -> lowest j, then min gid across lanes)
    float bestD = -3.4e38f; int bestJ = 0;
#pragma unroll
    for (int j = 0; j < NS; ++j)
        if (d[j] > bestD) { bestD = d[j]; bestJ = j; }
    u32 gid = (u32)((bestJ << 9) + t);
    u32 myOrd = ordf(bestD);
    u32 maxOrd = wave_umax_dpp(myOrd);
    u32 inv = (myOrd == maxOrd) ? (0xFFFFFFFFu - gid) : 0u;
    u32 maxInv = wave_umax_dpp(inv);
    if (lane == 0) rk64[0][w] = pack_key(maxOrd, maxInv, w);
    __syncthreads();

    for (int k = 0; k < KP; ++k) {
        int p = k & 1;
        // block winner among 8 wave candidates (uniform broadcast reads, u64 tree)
        u64 c0 = rk64[p][0], c1 = rk64[p][1], c2 = rk64[p][2], c3 = rk64[p][3];
        u64 c4 = rk64[p][4], c5 = rk64[p][5], c6 = rk64[p][6], c7 = rk64[p][7];
        u64 m0 = c0 > c1 ? c0 : c1;
        u64 m1 = c2 > c3 ? c2 : c3;
        u64 m2 = c4 > c5 ? c4 : c5;
        u64 m3 = c6 > c7 ? c6 : c7;
        u64 n0 = m0 > m1 ? m0 : m1;
        u64 n1 = m2 > m3 ? m2 : m3;
        u64 win = n0 > n1 ? n0 : n1;
        u32 wid = 0x3FFFu - ((u32)(win >> 3) & 0x3FFFu);
        float4 wq = cw[wid];          // uniform, L1/L2-hot
        float bx = wq.x, by = wq.y, bz = wq.z;
        if (t == 0) { kbuf[k * 3] = bx; kbuf[k * 3 + 1] = by; kbuf[k * 3 + 2] = bz; }

        // update + fused local argmax (exact: no fp contraction)
        bestD = -3.4e38f; bestJ = 0;
#pragma unroll
        for (int j = 0; j < NS; ++j) {
            float dx = px[j] - bx, dy = py[j] - by, dz = pz[j] - bz;
            float nd = ((dx * dx) + (dy * dy)) + (dz * dz);
            float dn = fminf(d[j], nd);
            d[j] = dn;
            if (dn > bestD) { bestD = dn; bestJ = j; }
        }
        gid = (u32)((bestJ << 9) + t);
        myOrd = ordf(bestD);
        maxOrd = wave_umax_dpp(myOrd);
        inv = (myOrd == maxOrd) ? (0xFFFFFFFFu - gid) : 0u;
        maxInv = wave_umax_dpp(inv);
        if (lane == 0) rk64[p ^ 1][w] = pack_key(maxOrd, maxInv, w);
        __syncthreads();
    }
    // flush keypoints LDS -> global (coalesced, once)
    for (int i = t; i < KP * 3; i += 512) kout[i] = kbuf[i];
}

// ---------------- K2: compaction (via global ws) + exact FPS ----------------
// 512 threads = 8 waves = 2 waves/SIMD.
__global__ void __launch_bounds__(512, 2)
k_fps(const float* __restrict__ pts, const unsigned char* __restrict__ flags,
      float4* __restrict__ cwg, float* __restrict__ kpOut) {
#pragma clang fp contract(off)
    __shared__ u64 rk64[2][8];
    __shared__ int wtot[8];
    __shared__ float kbuf[KP * 3];

    int b = blockIdx.x;
    int t = threadIdx.x;
    int lane = t & 63, w = t >> 6;
    int chunk = t * 32;   // 32 contiguous input points per thread
    const float* pbase = pts + (size_t)b * NPT * 5;
    const unsigned char* fbase = flags + b * NPT;
    float4* cw = cwg + (size_t)b * NPT;

    // pass 1: count valid in my chunk
    int cnt = 0;
    for (int j = 0; j < 32; ++j) cnt += fbase[chunk + j] ? 1 : 0;
    int incl = cnt;
#pragma unroll
    for (int off = 1; off < 64; off <<= 1) {
        int v = __shfl_up(incl, off, 64);
        if (lane >= off) incl += v;
    }
    if (lane == 63) wtot[w] = incl;
    __syncthreads();
    int waveBase = 0, V = 0;
    for (int i = 0; i < 8; ++i) { int wv = wtot[i]; V += wv; if (i < w) waveBase += wv; }
    int pos = waveBase + incl - cnt;

    // pass 2: stable scatter of compacted coords (float4) to global ws
    for (int j = 0; j < 32; ++j) {
        if (fbase[chunk + j]) {
            const float* pr = pbase + (size_t)(chunk + j) * 5;
            cw[pos] = make_float4(pr[0], pr[1], pr[2], 0.f);
            ++pos;
        }
    }
    __syncthreads();   // workgroup fence: scatter visible to block (write-through L1)

    float* kout = kpOut + (size_t)b * KP * 3;
    if (V == 0) {      // degenerate: reference picks index 0 every step
        if (t == 0)
            for (int k = 0; k < KP; ++k) {
                kout[k * 3] = pbase[0]; kout[k * 3 + 1] = pbase[1]; kout[k * 3 + 2] = pbase[2];
            }
        return;
    }
    int jm = (V + 511) >> 9;
    if (jm <= 10)      fps_loop<10>(t, lane, w, V, cw, rk64, kbuf, kout);
    else if (jm <= 12) fps_loop<12>(t, lane, w, V, cw, rk64, kbuf, kout);
    else if (jm <= 14) fps_loop<14>(t, lane, w, V, cw, rk64, kbuf, kout);
    else if (jm <= 16) fps_loop<16>(t, lane, w, V, cw, rk64, kbuf, kout);
    else if (jm <= 24) fps_loop<24>(t, lane, w, V, cw, rk64, kbuf, kout);
    else               fps_loop<32>(t, lane, w, V, cw, rk64, kbuf, kout);
}

// ---------------- K3: bilinear BEV sampling ----------------
__global__ void k_bilinear(const float* __restrict__ sf, const float* __restrict__ kp,
                           float* __restrict__ feats) {
    int bid = blockIdx.x;
    int b = bid >> 11, kk = bid & 2047;
    int c = threadIdx.x;
    const float* kpr = kp + (size_t)(b * KP + kk) * 3;
    float x = kpr[0], y = kpr[1];
    float xi = ((x - (-75.2f)) / 0.1f) / 8.0f;
    float yi = ((y - (-75.2f)) / 0.1f) / 8.0f;
    int x0 = (int)floorf(xi); x0 = min(max(x0, 0), 187);
    int x1 = min(max(x0 + 1, 0), 187);
    int y0 = (int)floorf(yi); y0 = min(max(y0, 0), 187);
    int y1 = min(max(y0 + 1, 0), 187);
    float xf0 = (float)x0, xf1 = (float)x1, yf0 = (float)y0, yf1 = (float)y1;
    float wa = (xf1 - xi) * (yf1 - yi), wb = (xf1 - xi) * (yi - yf0);
    float wc = (xi - xf0) * (yf1 - yi), wd = (xi - xf0) * (yi - yf0);
    const float* plane = sf + (size_t)(b * 256 + c) * 188 * 188;
    float Ia = plane[y0 * 188 + x0], Ib = plane[y1 * 188 + x0];
    float Ic = plane[y0 * 188 + x1], Id = plane[y1 * 188 + x1];
    feats[(size_t)(b * KP + kk) * 352 + c] = Ia * wa + Ib * wb + Ic * wc + Id * wd;
}

// ---------------- K4a: raw point feature MLP ----------------
__global__ void k_fraw(const float* __restrict__ pts, const float* __restrict__ Wr,
                       const float* __restrict__ br, float* __restrict__ fraw) {
    int idx = blockIdx.x * 256 + threadIdx.x;   // < BN_*NPT*32
    int c = idx & 31, n = idx >> 5;
    const float* pr = pts + (size_t)n * 5;
    float v = pr[3] * Wr[c] + pr[4] * Wr[32 + c] + br[c];
    fraw[(size_t)n * 32 + c] = fmaxf(v, 0.f);
}

// ---------------- K4b: conv3 point feature MLP ----------------
__global__ void k_gc3(const float* __restrict__ conv3, const float* __restrict__ Wc,
                      const float* __restrict__ bc, float* __restrict__ gc3) {
    __shared__ float w[4096];
    __shared__ float rf[4][64];
    int t = threadIdx.x;
    for (int i = t; i < 4096; i += 256) w[i] = Wc[i];
    int r = blockIdx.x * 4 + (t >> 6);
    int c = t & 63;
    rf[t >> 6][c] = conv3[(size_t)r * 67 + 3 + c];
    __syncthreads();
    float s = bc[c];
#pragma unroll 8
    for (int k = 0; k < 64; ++k) s = fmaf(rf[t >> 6][k], w[k * 64 + c], s);
    gc3[(size_t)r * 64 + c] = fmaxf(s, 0.f);
}

// ---------------- K5: raw radius aggregation ----------------
__global__ void k_rawagg(const float* __restrict__ pts, const float* __restrict__ kp,
                         const float* __restrict__ fraw, float* __restrict__ feats,
                         float* __restrict__ cntR) {
    __shared__ float sp[2560];
    int bid = blockIdx.x;
    int b = bid >> 7, kb = (bid >> 4) & 7, s = bid & 15;
    int t = threadIdx.x;
    int kk = kb * 256 + t, row = b * KP + kk;
    float kx = kp[row * 3], ky = kp[row * 3 + 1], kz = kp[row * 3 + 2];
    float acc[32];
#pragma unroll
    for (int c = 0; c < 32; ++c) acc[c] = 0.f;
    float cnt = 0.f;
    const float R2 = 0.8f * 0.8f;
    for (int tile = 0; tile < 2; ++tile) {
        int nbase = s * 1024 + tile * 512;
        const float* src = pts + (size_t)(b * NPT + nbase) * 5;
        for (int i = t; i < 2560; i += 256) sp[i] = src[i];
        __syncthreads();
        for (int j = 0; j < 512; ++j) {
            float dx = kx - sp[j * 5], dy = ky - sp[j * 5 + 1], dz = kz - sp[j * 5 + 2];
            float d2 = fmaf(dx, dx, fmaf(dy, dy, dz * dz));
            if (d2 < R2) {
                cnt += 1.f;
                const float* fp = fraw + (size_t)(b * NPT + nbase + j) * 32;
#pragma unroll
                for (int c = 0; c < 32; ++c) acc[c] += fp[c];
            }
        }
        __syncthreads();
    }
    float* dst = feats + (size_t)row * 352 + 256;
#pragma unroll
    for (int c = 0; c < 32; ++c) if (acc[c] != 0.f) atomicAdd(dst + c, acc[c]);
    if (cnt != 0.f) atomicAdd(cntR + row, cnt);
}

// ---------------- K6: conv3 radius aggregation ----------------
__global__ void k_c3agg(const float* __restrict__ conv3, const float* __restrict__ kp,
                        const float* __restrict__ gc3, float* __restrict__ feats,
                        float* __restrict__ cntC) {
    __shared__ float sq[256 * 3];
    int bid = blockIdx.x;
    int b = bid >> 7, kb = (bid >> 4) & 7, s = bid & 15;
    int t = threadIdx.x;
    int kk = kb * 256 + t, row = b * KP + kk;
    float kx = kp[row * 3], ky = kp[row * 3 + 1], kz = kp[row * 3 + 2];
    float acc[64];
#pragma unroll
    for (int c = 0; c < 64; ++c) acc[c] = 0.f;
    float cnt = 0.f;
    const float R2 = 1.6f * 1.6f;
    for (int tile = 0; tile < 2; ++tile) {
        int nbase = s * 512 + tile * 256;
        const float* src = conv3 + (size_t)(b * MPT + nbase + t) * 67;
        sq[t * 3] = src[0]; sq[t * 3 + 1] = src[1]; sq[t * 3 + 2] = src[2];
        __syncthreads();
        for (int j = 0; j < 256; ++j) {
            float dx = kx - sq[j * 3], dy = ky - sq[j * 3 + 1], dz = kz - sq[j * 3 + 2];
            float d2 = fmaf(dx, dx, fmaf(dy, dy, dz * dz));
            if (d2 < R2) {
                cnt += 1.f;
                const float* gp = gc3 + (size_t)(b * MPT + nbase + j) * 64;
#pragma unroll
                for (int c = 0; c < 64; ++c) acc[c] += gp[c];
            }
        }
        __syncthreads();
    }
    float* dst = feats + (size_t)row * 352 + 288;
#pragma unroll
    for (int c = 0; c < 64; ++c) if (acc[c] != 0.f) atomicAdd(dst + c, acc[c]);
    if (cnt != 0.f) atomicAdd(cntC + row, cnt);
}

// ---------------- K7: fuse GEMM + BN + ReLU ----------------
__global__ void k_fuse(const float* __restrict__ feats, const float* __restrict__ cntR,
                       const float* __restrict__ cntC, const float* __restrict__ Wf,
                       const float* __restrict__ gma, const float* __restrict__ bta,
                       const float* __restrict__ mean, const float* __restrict__ var,
                       float* __restrict__ out) {
    __shared__ float a[2][352];
    int r0 = blockIdx.x * 2;
    int t = threadIdx.x;
    for (int i = t; i < 704; i += 256) {
        int rr = i >= 352 ? 1 : 0;
        int k = i - rr * 352;
        float v = feats[(size_t)(r0 + rr) * 352 + k];
        if (k >= 256) {
            float cn = (k < 288) ? cntR[r0 + rr] : cntC[r0 + rr];
            v = v / fmaxf(cn, 1.0f);
        }
        a[rr][k] = v;
    }
    __syncthreads();
    int r = t >> 7, c = t & 127;
    float s = 0.f;
#pragma unroll 4
    for (int k = 0; k < 352; ++k) s = fmaf(a[r][k], Wf[k * 128 + c], s);
    s = (s - mean[c]) * (1.0f / sqrtf(var[c] + 1e-5f)) * gma[c] + bta[c];
    out[(size_t)(r0 + r) * 128 + c] = fmaxf(s, 0.f);
}

// ---------------- launch ----------------
extern "C" void kernel_launch(void* const* d_in, const int* in_sizes, int n_in,
                              void* d_out, int out_size, void* d_ws, size_t ws_size,
                              hipStream_t stream) {
    const float* pts   = (const float*)d_in[0];
    const float* bbox  = (const float*)d_in[1];
    const float* sf    = (const float*)d_in[2];
    const float* conv3 = (const float*)d_in[3];
    const float* Wraw  = (const float*)d_in[4];
    const float* braw  = (const float*)d_in[5];
    const float* Wc3   = (const float*)d_in[6];
    const float* bc3   = (const float*)d_in[7];
    const float* Wf    = (const float*)d_in[8];
    const float* gma   = (const float*)d_in[9];
    const float* bta   = (const float*)d_in[10];
    const float* mean  = (const float*)d_in[11];
    const float* var   = (const float*)d_in[12];

    float* wsf   = (float*)d_ws;
    float* feats = wsf;
    float* cntR  = wsf + CNTR_OFF;
    float* cntC  = wsf + CNTC_OFF;
    float* fraw  = wsf + FRAW_OFF;
    float* gc3   = wsf + GC3_OFF;
    unsigned char* flags = (unsigned char*)(wsf + FLAGS_F_OFF);
    float4* cwg  = (float4*)(wsf + CW_OFF);

    float* outp  = (float*)d_out;
    float* kpOut = outp + OUT_KP_OFF;

    // zero feats + counters (atomically accumulated later)
    hipMemsetAsync(d_ws, 0, (size_t)(FEATS_LEN + 8192) * 4, stream);

    k_flags<<<BN_ * 64, 256, 0, stream>>>(pts, bbox, flags);
    k_fps<<<BN_, 512, 0, stream>>>(pts, flags, cwg, kpOut);
    k_bilinear<<<BN_ * KP, 256, 0, stream>>>(sf, kpOut, feats);
    k_fraw<<<(BN_ * NPT * 32) / 256, 256, 0, stream>>>(pts, Wraw, braw, fraw);
    k_gc3<<<(BN_ * MPT) / 4, 256, 0, stream>>>(conv3, Wc3, bc3, gc3);
    k_rawagg<<<BN_ * 128, 256, 0, stream>>>(pts, kpOut, fraw, feats, cntR);
    k_c3agg<<<BN_ * 128, 256, 0, stream>>>(conv3, kpOut, gc3, feats, cntC);
    k_fuse<<<2048, 256, 0, stream>>>(feats, cntR, cntC, Wf, gma, bta, mean, var, outp);
}